// Round 6
// baseline (156.893 us; speedup 1.0000x reference)
//
#include <hip/hip_runtime.h>

#define NPTS 32768

typedef _Float16 f16;
typedef _Float16 f16x2 __attribute__((ext_vector_type(2)));
typedef _Float16 f16x8 __attribute__((ext_vector_type(8)));
typedef float f32x2 __attribute__((ext_vector_type(2)));
typedef float f32x4 __attribute__((ext_vector_type(4)));
typedef unsigned int u32x4 __attribute__((ext_vector_type(4)));

union U16 { u32x4 u; f32x4 f; f16x2 h2[4]; f16x8 h8; };

static __device__ __forceinline__ f16x2 pk_fma(f16x2 a, f16x2 b, f16x2 c) {
  return __builtin_elementwise_fma(a, b, c);
}
static __device__ __forceinline__ f16x2 pk_relu(f16x2 a) {
  f16x2 z = {(f16)0.f, (f16)0.f};
  return __builtin_elementwise_max(a, z);
}
static __device__ __forceinline__ f16x2 pk_cvt(float a, float b) {
  return __builtin_bit_cast(f16x2, __builtin_amdgcn_cvt_pkrtz(a, b));
}

// Per used-gas (gi = 0..73) tables (h2o nets 7,8 unused downstream):
__device__ const unsigned char G_T[74] = {
  0,0,0,0,0,0,0, 0,0,0,0,0,0,0,0,0,0,0,0,0,0,0,0,0,0,0,0,
  1,1,1,1,1,1,1,1,1,1,1,1,1,
  2,2,2,2,2,2,2,2,2,
  3,3,3,
  4,4,4,4,4,4,4,4,4,
  5,5,5,5,5,5,5,5,5,5,5,5,5
};
__device__ const unsigned char G_C1[74] = {
  0,1,2,3,4,5,6, 9,10,11,12,13,14,15,16,17,18,19,20,21,22,23,24,25,26,27,28,
  0,1,2,17,18,19,20,21,22,25,26,27,28,
  0,1,2,5,6,9,10,13,14,
  0,1,2,
  0,1,2,3,4,7,8,11,12,
  0,1,2,15,16,17,18,19,20,21,22,27,28
};
__device__ const unsigned char G_C2[74] = {
  255,255,255,7,8,255,255, 255,255,255,255,255,255,255,255,255,255,255,255,
  255,255,255,255,255,255,255,255,
  255,255,255,255,255,255,255,255,255,255,255,255,255,
  255,255,255,255,255,255,255,255,255,
  255,255,255,
  255,255,255,255,255,255,255,255,255,
  255,255,255,255,255,255,255,255,255,255,255,255,255
};

// Packed-weight layout in d_ws: uint4 slots, addr = ((gi*22 + slot)*64 + lane).
// slots 0..7  : afrag[mt][ks] (f16x8), slot = mt*2+ks
// slots 8..9  : w0h[ks][0..3] (4 f16x2)
// slots 10..11: w1h[ks][0..3]
// slots 12..13: b1h[ks][0..3]
// slots 14..17: b2q[mt] (f32x4)
// slots 18..21: wq[mt]  (f32x4)
#define NSLOT 22

// ---------------------------------------------------------------------------
// k0w: repack weights into fragment-ready lane order. 74 blocks x 64 threads.
// ---------------------------------------------------------------------------
__global__ __launch_bounds__(64) void k0w_pack(
    const float* __restrict__ W1, const float* __restrict__ b1,
    const float* __restrict__ W2, const float* __restrict__ b2,
    const float* __restrict__ Wout, u32x4* __restrict__ pack)
{
  const int gi   = blockIdx.x;
  const int lane = threadIdx.x;
  const int l15  = lane & 15;
  const int quad = lane >> 4;
  const int g    = gi + (gi >= 7 ? 2 : 0);

  const float* W2g = W2 + g * 4096;
  const float* W1g = W1 + g * 128;
  const float* b1g = b1 + g * 64;
  u32x4* dst = pack + gi * NSLOT * 64 + lane;

  // afrag slots
  #pragma unroll
  for (int mt = 0; mt < 4; ++mt)
    #pragma unroll
    for (int ks = 0; ks < 2; ++ks) {
      U16 u;
      #pragma unroll
      for (int j = 0; j < 4; ++j) {
        const float* s = W2g + (ks * 32 + quad * 8 + 2 * j) * 64 + mt * 16 + l15;
        u.h2[j] = pk_cvt(s[0], s[64]);
      }
      dst[(mt * 2 + ks) * 64] = u.u;
    }
  // layer-1 slots
  #pragma unroll
  for (int ks = 0; ks < 2; ++ks) {
    U16 a, b, c;
    #pragma unroll
    for (int j = 0; j < 4; ++j) {
      int h = ks * 32 + quad * 8 + 2 * j;
      a.h2[j] = pk_cvt(W1g[h],      W1g[h + 1]);
      b.h2[j] = pk_cvt(W1g[64 + h], W1g[64 + h + 1]);
      c.h2[j] = pk_cvt(b1g[h],      b1g[h + 1]);
    }
    dst[(8 + ks) * 64]  = a.u;
    dst[(10 + ks) * 64] = b.u;
    dst[(12 + ks) * 64] = c.u;
  }
  // b2 / Wout slots (f32)
  #pragma unroll
  for (int mt = 0; mt < 4; ++mt) {
    U16 u, v;
    u.f = *(const f32x4*)(b2   + g * 64 + mt * 16 + quad * 4);
    v.f = *(const f32x4*)(Wout + g * 64 + mt * 16 + quad * 4);
    dst[(14 + mt) * 64] = u.u;
    dst[(18 + mt) * 64] = v.u;
  }
}

// ---------------------------------------------------------------------------
// k0: zero the gases section of out, write tau_lw / tau_iw.
// ---------------------------------------------------------------------------
__global__ __launch_bounds__(256) void k0_init(
    const float* __restrict__ comp, const float* __restrict__ ke_lw,
    const float* __restrict__ ke_iw, float* __restrict__ out)
{
  const int c = blockIdx.x >> 7;
  const int n = ((blockIdx.x & 127) << 8) + threadIdx.x;
  out[c * NPTS + n] = 0.f;
  out[29 * NPTS + c * NPTS + n] = ke_lw[c] * comp[6 * NPTS + n];
  out[58 * NPTS + c * NPTS + n] = ke_iw[c] * comp[7 * NPTS + n];
}

// ---------------------------------------------------------------------------
// k1: per-gas MLP (2->64->64->1) fused with channel scatter.
// Preamble = 22 coalesced dwordx4 loads of pre-packed fragments.
// Per-mt accumulator folding keeps acc liveness at 16 regs (VGPR-resident).
// 512 points/wave (8 passes), 4736 waves, 1184 blocks.
// ---------------------------------------------------------------------------
__global__ __launch_bounds__(256, 4) void k1_mlp(
    const float* __restrict__ t_p, const float* __restrict__ comp,
    const u32x4* __restrict__ pack, const float* __restrict__ bout,
    float* __restrict__ out)
{
  const int lane = threadIdx.x & 63;
  const int l15  = lane & 15;
  const int quad = lane >> 4;
  const int w    = blockIdx.x * 4 + (threadIdx.x >> 6);
  const int gi   = w >> 6;                 // 0..73
  const int g    = gi + (gi >= 7 ? 2 : 0);
  const int pb0  = (w & 63) * 512;

  const int t  = G_T[gi];
  const int c1 = G_C1[gi];
  const int c2 = G_C2[gi];   // 255 = none

  const bool qb0 = (quad & 1) != 0;
  const bool qb1 = (quad & 2) != 0;

  // ---- coalesced fragment loads
  const u32x4* pksrc = pack + gi * NSLOT * 64 + lane;
  U16 slot[NSLOT];
  #pragma unroll
  for (int i = 0; i < NSLOT; ++i)
    slot[i].u = pksrc[i * 64];

  f16x8 afrag[4][2];
  f32x4 b2q[4];
  f32x2 wq2[4][2];
  #pragma unroll
  for (int mt = 0; mt < 4; ++mt) {
    afrag[mt][0] = slot[mt * 2 + 0].h8;
    afrag[mt][1] = slot[mt * 2 + 1].h8;
    b2q[mt] = slot[14 + mt].f;
    wq2[mt][0] = f32x2{ slot[18 + mt].f[0], slot[18 + mt].f[1] };
    wq2[mt][1] = f32x2{ slot[18 + mt].f[2], slot[18 + mt].f[3] };
  }
  f16x2 w0h[2][4], w1h[2][4], b1h[2][4];
  #pragma unroll
  for (int ks = 0; ks < 2; ++ks)
    #pragma unroll
    for (int j = 0; j < 4; ++j) {
      w0h[ks][j] = slot[8 + ks].h2[j];
      w1h[ks][j] = slot[10 + ks].h2[j];
      b1h[ks][j] = slot[12 + ks].h2[j];
    }
  const float bo = bout[g];

  const float2* tp2 = (const float2*)t_p;
  const float* compt = comp + t * NPTS;
  float* out1 = out + c1 * NPTS;
  float* out2 = (c2 == 255) ? nullptr : out + c2 * NPTS;

  for (int pass = 0; pass < 8; ++pass) {
    const int pb = pb0 + pass * 64;

    float2 xv[4];
    #pragma unroll
    for (int pt = 0; pt < 4; ++pt)
      xv[pt] = tp2[pb + pt * 16 + l15];
    const float cv = compt[pb + lane];

    f16x2 x0v[4], x1v[4];
    #pragma unroll
    for (int pt = 0; pt < 4; ++pt) {
      x0v[pt] = pk_cvt(xv[pt].x, xv[pt].x);
      x1v[pt] = pk_cvt(xv[pt].y, xv[pt].y);
    }

    // layer 1 -> B fragments (k = ks*32 + quad*8 + j-pair)
    U16 bfrag[2][4];
    #pragma unroll
    for (int ks = 0; ks < 2; ++ks)
      #pragma unroll
      for (int pt = 0; pt < 4; ++pt)
        #pragma unroll
        for (int i = 0; i < 4; ++i)
          bfrag[ks][pt].h2[i] =
              pk_relu(pk_fma(x0v[pt], w0h[ks][i], pk_fma(x1v[pt], w1h[ks][i], b1h[ks][i])));

    // layer 2 + per-mt layer-3 fold (acc liveness = 16 regs)
    f32x2 p2[4];
    #pragma unroll
    for (int pt = 0; pt < 4; ++pt) p2[pt] = f32x2{ 0.f, 0.f };

    #pragma unroll
    for (int mt = 0; mt < 4; ++mt) {
      f32x4 c[4];
      #pragma unroll
      for (int pt = 0; pt < 4; ++pt)
        c[pt] = __builtin_amdgcn_mfma_f32_16x16x32_f16(
            afrag[mt][0], bfrag[0][pt].h8, b2q[mt], 0, 0, 0);
      #pragma unroll
      for (int pt = 0; pt < 4; ++pt)
        c[pt] = __builtin_amdgcn_mfma_f32_16x16x32_f16(
            afrag[mt][1], bfrag[1][pt].h8, c[pt], 0, 0, 0);
      #pragma unroll
      for (int pt = 0; pt < 4; ++pt) {
        f32x2 z = { 0.f, 0.f };
        f32x2 a0 = { c[pt][0], c[pt][1] };
        f32x2 a1 = { c[pt][2], c[pt][3] };
        a0 = __builtin_elementwise_max(a0, z);
        a1 = __builtin_elementwise_max(a1, z);
        p2[pt] = __builtin_elementwise_fma(a0, wq2[mt][0], p2[pt]);
        p2[pt] = __builtin_elementwise_fma(a1, wq2[mt][1], p2[pt]);
      }
    }

    float p[4];
    #pragma unroll
    for (int pt = 0; pt < 4; ++pt) p[pt] = p2[pt][0] + p2[pt][1];

    // quad transpose-reduce: 3 shuffles
    float u  = qb1 ? (qb0 ? p[3] : p[2]) : (qb0 ? p[1] : p[0]);
    float v  = qb1 ? (qb0 ? p[2] : p[3]) : (qb0 ? p[0] : p[1]);
    float w2 = qb1 ? (qb0 ? p[1] : p[0]) : (qb0 ? p[3] : p[2]);
    float x  = qb1 ? (qb0 ? p[0] : p[1]) : (qb0 ? p[2] : p[3]);
    float s  = u + __shfl_xor(v, 16, 64);
    float tt = w2 + __shfl_xor(x, 16, 64);
    float r  = s + __shfl_xor(tt, 32, 64);

    float tau = fmaxf(r + bo, 0.f) * cv;
    atomicAdd(&out1[pb + lane], tau);
    if (out2) atomicAdd(&out2[pb + lane], tau);
  }
}

// ---------------------------------------------------------------------------
extern "C" void kernel_launch(void* const* d_in, const int* in_sizes, int n_in,
                              void* d_out, int out_size, void* d_ws, size_t ws_size,
                              hipStream_t stream)
{
  const float* t_p   = (const float*)d_in[0];
  const float* comp  = (const float*)d_in[1];
  const float* W1    = (const float*)d_in[2];
  const float* b1    = (const float*)d_in[3];
  const float* W2    = (const float*)d_in[4];
  const float* b2    = (const float*)d_in[5];
  const float* Wout  = (const float*)d_in[6];
  const float* bout  = (const float*)d_in[7];
  const float* ke_lw = (const float*)d_in[8];
  const float* ke_iw = (const float*)d_in[9];
  float* out = (float*)d_out;
  u32x4* pack = (u32x4*)d_ws;   // 74*22*64*16 B = 1.63 MB

  k0w_pack<<<74, 64, 0, stream>>>(W1, b1, W2, b2, Wout, pack);
  k0_init<<<29 * 128, 256, 0, stream>>>(comp, ke_lw, ke_iw, out);
  k1_mlp<<<1184, 256, 0, stream>>>(t_p, comp, pack, bout, out);
}

// Round 7
// 113.642 us; speedup vs baseline: 1.3806x; 1.3806x over previous
//
#include <hip/hip_runtime.h>

#define NPTS 32768

typedef _Float16 f16;
typedef _Float16 f16x2 __attribute__((ext_vector_type(2)));
typedef _Float16 f16x8 __attribute__((ext_vector_type(8)));
typedef float f32x2 __attribute__((ext_vector_type(2)));
typedef float f32x4 __attribute__((ext_vector_type(4)));
typedef unsigned int u32x4 __attribute__((ext_vector_type(4)));

union U16 { u32x4 u; f32x4 f; f16x2 h2[4]; f16x8 h8; };

static __device__ __forceinline__ f16x2 pk_fma(f16x2 a, f16x2 b, f16x2 c) {
  return __builtin_elementwise_fma(a, b, c);
}
static __device__ __forceinline__ f16x2 pk_relu(f16x2 a) {
  f16x2 z = {(f16)0.f, (f16)0.f};
  return __builtin_elementwise_max(a, z);
}
static __device__ __forceinline__ f16x2 pk_cvt(float a, float b) {
  return __builtin_bit_cast(f16x2, __builtin_amdgcn_cvt_pkrtz(a, b));
}

// Per used-gas (gi = 0..73) tables (h2o nets 7,8 unused downstream):
__device__ const unsigned char G_T[74] = {
  0,0,0,0,0,0,0, 0,0,0,0,0,0,0,0,0,0,0,0,0,0,0,0,0,0,0,0,
  1,1,1,1,1,1,1,1,1,1,1,1,1,
  2,2,2,2,2,2,2,2,2,
  3,3,3,
  4,4,4,4,4,4,4,4,4,
  5,5,5,5,5,5,5,5,5,5,5,5,5
};
__device__ const unsigned char G_C1[74] = {
  0,1,2,3,4,5,6, 9,10,11,12,13,14,15,16,17,18,19,20,21,22,23,24,25,26,27,28,
  0,1,2,17,18,19,20,21,22,25,26,27,28,
  0,1,2,5,6,9,10,13,14,
  0,1,2,
  0,1,2,3,4,7,8,11,12,
  0,1,2,15,16,17,18,19,20,21,22,27,28
};
__device__ const unsigned char G_C2[74] = {
  255,255,255,7,8,255,255, 255,255,255,255,255,255,255,255,255,255,255,255,
  255,255,255,255,255,255,255,255,
  255,255,255,255,255,255,255,255,255,255,255,255,255,
  255,255,255,255,255,255,255,255,255,
  255,255,255,
  255,255,255,255,255,255,255,255,255,
  255,255,255,255,255,255,255,255,255,255,255,255,255
};

// Packed-weight layout in d_ws: uint4 slots, addr = ((gi*22 + slot)*64 + lane).
// slots 0..7  : afrag[mt][ks] (f16x8), slot = mt*2+ks
// slots 8..9  : w0h[ks][0..3] (4 f16x2)
// slots 10..11: w1h[ks][0..3]
// slots 12..13: b1h[ks][0..3]
// slots 14..17: b2q[mt] (f32x4)
// slots 18..21: wq[mt]  (f32x4)
#define NSLOT 22

// ---------------------------------------------------------------------------
// k0w: repack weights into fragment-ready lane order. 74 blocks x 64 threads.
// ---------------------------------------------------------------------------
__global__ __launch_bounds__(64) void k0w_pack(
    const float* __restrict__ W1, const float* __restrict__ b1,
    const float* __restrict__ W2, const float* __restrict__ b2,
    const float* __restrict__ Wout, u32x4* __restrict__ pack)
{
  const int gi   = blockIdx.x;
  const int lane = threadIdx.x;
  const int l15  = lane & 15;
  const int quad = lane >> 4;
  const int g    = gi + (gi >= 7 ? 2 : 0);

  const float* W2g = W2 + g * 4096;
  const float* W1g = W1 + g * 128;
  const float* b1g = b1 + g * 64;
  u32x4* dst = pack + gi * NSLOT * 64 + lane;

  #pragma unroll
  for (int mt = 0; mt < 4; ++mt)
    #pragma unroll
    for (int ks = 0; ks < 2; ++ks) {
      U16 u;
      #pragma unroll
      for (int j = 0; j < 4; ++j) {
        const float* s = W2g + (ks * 32 + quad * 8 + 2 * j) * 64 + mt * 16 + l15;
        u.h2[j] = pk_cvt(s[0], s[64]);
      }
      dst[(mt * 2 + ks) * 64] = u.u;
    }
  #pragma unroll
  for (int ks = 0; ks < 2; ++ks) {
    U16 a, b, c;
    #pragma unroll
    for (int j = 0; j < 4; ++j) {
      int h = ks * 32 + quad * 8 + 2 * j;
      a.h2[j] = pk_cvt(W1g[h],      W1g[h + 1]);
      b.h2[j] = pk_cvt(W1g[64 + h], W1g[64 + h + 1]);
      c.h2[j] = pk_cvt(b1g[h],      b1g[h + 1]);
    }
    dst[(8 + ks) * 64]  = a.u;
    dst[(10 + ks) * 64] = b.u;
    dst[(12 + ks) * 64] = c.u;
  }
  #pragma unroll
  for (int mt = 0; mt < 4; ++mt) {
    U16 u, v;
    u.f = *(const f32x4*)(b2   + g * 64 + mt * 16 + quad * 4);
    v.f = *(const f32x4*)(Wout + g * 64 + mt * 16 + quad * 4);
    dst[(14 + mt) * 64] = u.u;
    dst[(18 + mt) * 64] = v.u;
  }
}

// ---------------------------------------------------------------------------
// k0: zero the gases section of out, write tau_lw / tau_iw.
// ---------------------------------------------------------------------------
__global__ __launch_bounds__(256) void k0_init(
    const float* __restrict__ comp, const float* __restrict__ ke_lw,
    const float* __restrict__ ke_iw, float* __restrict__ out)
{
  const int c = blockIdx.x >> 7;
  const int n = ((blockIdx.x & 127) << 8) + threadIdx.x;
  out[c * NPTS + n] = 0.f;
  out[29 * NPTS + c * NPTS + n] = ke_lw[c] * comp[6 * NPTS + n];
  out[58 * NPTS + c * NPTS + n] = ke_iw[c] * comp[7 * NPTS + n];
}

// ---------------------------------------------------------------------------
// k1: per-gas MLP (2->64->64->1) fused with channel scatter.
// Preamble = 22 coalesced dwordx4 loads of pre-packed fragments, loaded
// directly into typed registers. Per-mt accumulator folding (acc liveness
// 16 regs). 512 points/wave (8 passes), 4736 waves, 1184 blocks.
// NOTE: (256,2) bound — (256,4) capped VGPRs at 64 and spilled to scratch
// (R6: FETCH 90 MB, 85 us). Do not lower the register budget.
// ---------------------------------------------------------------------------
__global__ __launch_bounds__(256, 2) void k1_mlp(
    const float* __restrict__ t_p, const float* __restrict__ comp,
    const u32x4* __restrict__ pack, const float* __restrict__ bout,
    float* __restrict__ out)
{
  const int lane = threadIdx.x & 63;
  const int l15  = lane & 15;
  const int quad = lane >> 4;
  const int w    = blockIdx.x * 4 + (threadIdx.x >> 6);
  const int gi   = w >> 6;                 // 0..73
  const int g    = gi + (gi >= 7 ? 2 : 0);
  const int pb0  = (w & 63) * 512;

  const int t  = G_T[gi];
  const int c1 = G_C1[gi];
  const int c2 = G_C2[gi];   // 255 = none

  const bool qb0 = (quad & 1) != 0;
  const bool qb1 = (quad & 2) != 0;

  // ---- coalesced fragment loads, directly into typed registers
  const u32x4* pksrc = pack + gi * NSLOT * 64 + lane;
  f16x8 afrag[4][2];
  f32x4 b2q[4];
  f32x2 wq2[4][2];
  #pragma unroll
  for (int mt = 0; mt < 4; ++mt) {
    afrag[mt][0] = __builtin_bit_cast(f16x8, pksrc[(mt * 2 + 0) * 64]);
    afrag[mt][1] = __builtin_bit_cast(f16x8, pksrc[(mt * 2 + 1) * 64]);
    b2q[mt] = __builtin_bit_cast(f32x4, pksrc[(14 + mt) * 64]);
    f32x4 wv = __builtin_bit_cast(f32x4, pksrc[(18 + mt) * 64]);
    wq2[mt][0] = f32x2{ wv[0], wv[1] };
    wq2[mt][1] = f32x2{ wv[2], wv[3] };
  }
  U16 w0s[2], w1s[2], b1s[2];
  #pragma unroll
  for (int ks = 0; ks < 2; ++ks) {
    w0s[ks].u = pksrc[(8 + ks) * 64];
    w1s[ks].u = pksrc[(10 + ks) * 64];
    b1s[ks].u = pksrc[(12 + ks) * 64];
  }
  const float bo = bout[g];

  const float2* tp2 = (const float2*)t_p;
  const float* compt = comp + t * NPTS;
  float* out1 = out + c1 * NPTS;
  float* out2 = (c2 == 255) ? nullptr : out + c2 * NPTS;

  for (int pass = 0; pass < 8; ++pass) {
    const int pb = pb0 + pass * 64;

    float2 xv[4];
    #pragma unroll
    for (int pt = 0; pt < 4; ++pt)
      xv[pt] = tp2[pb + pt * 16 + l15];
    const float cv = compt[pb + lane];

    f16x2 x0v[4], x1v[4];
    #pragma unroll
    for (int pt = 0; pt < 4; ++pt) {
      x0v[pt] = pk_cvt(xv[pt].x, xv[pt].x);
      x1v[pt] = pk_cvt(xv[pt].y, xv[pt].y);
    }

    // layer 1 -> B fragments (k = ks*32 + quad*8 + j-pair)
    U16 bfrag[2][4];
    #pragma unroll
    for (int ks = 0; ks < 2; ++ks)
      #pragma unroll
      for (int pt = 0; pt < 4; ++pt)
        #pragma unroll
        for (int i = 0; i < 4; ++i)
          bfrag[ks][pt].h2[i] =
              pk_relu(pk_fma(x0v[pt], w0s[ks].h2[i],
                             pk_fma(x1v[pt], w1s[ks].h2[i], b1s[ks].h2[i])));

    // layer 2 + per-mt layer-3 fold (acc liveness = 16 regs)
    f32x2 p2[4];
    #pragma unroll
    for (int pt = 0; pt < 4; ++pt) p2[pt] = f32x2{ 0.f, 0.f };

    #pragma unroll
    for (int mt = 0; mt < 4; ++mt) {
      f32x4 c[4];
      #pragma unroll
      for (int pt = 0; pt < 4; ++pt)
        c[pt] = __builtin_amdgcn_mfma_f32_16x16x32_f16(
            afrag[mt][0], bfrag[0][pt].h8, b2q[mt], 0, 0, 0);
      #pragma unroll
      for (int pt = 0; pt < 4; ++pt)
        c[pt] = __builtin_amdgcn_mfma_f32_16x16x32_f16(
            afrag[mt][1], bfrag[1][pt].h8, c[pt], 0, 0, 0);
      #pragma unroll
      for (int pt = 0; pt < 4; ++pt) {
        f32x2 z = { 0.f, 0.f };
        f32x2 a0 = { c[pt][0], c[pt][1] };
        f32x2 a1 = { c[pt][2], c[pt][3] };
        a0 = __builtin_elementwise_max(a0, z);
        a1 = __builtin_elementwise_max(a1, z);
        p2[pt] = __builtin_elementwise_fma(a0, wq2[mt][0], p2[pt]);
        p2[pt] = __builtin_elementwise_fma(a1, wq2[mt][1], p2[pt]);
      }
    }

    float p[4];
    #pragma unroll
    for (int pt = 0; pt < 4; ++pt) p[pt] = p2[pt][0] + p2[pt][1];

    // quad transpose-reduce: 3 shuffles
    float u  = qb1 ? (qb0 ? p[3] : p[2]) : (qb0 ? p[1] : p[0]);
    float v  = qb1 ? (qb0 ? p[2] : p[3]) : (qb0 ? p[0] : p[1]);
    float w2 = qb1 ? (qb0 ? p[1] : p[0]) : (qb0 ? p[3] : p[2]);
    float x  = qb1 ? (qb0 ? p[0] : p[1]) : (qb0 ? p[2] : p[3]);
    float s  = u + __shfl_xor(v, 16, 64);
    float tt = w2 + __shfl_xor(x, 16, 64);
    float r  = s + __shfl_xor(tt, 32, 64);

    float tau = fmaxf(r + bo, 0.f) * cv;
    atomicAdd(&out1[pb + lane], tau);
    if (out2) atomicAdd(&out2[pb + lane], tau);
  }
}

// ---------------------------------------------------------------------------
extern "C" void kernel_launch(void* const* d_in, const int* in_sizes, int n_in,
                              void* d_out, int out_size, void* d_ws, size_t ws_size,
                              hipStream_t stream)
{
  const float* t_p   = (const float*)d_in[0];
  const float* comp  = (const float*)d_in[1];
  const float* W1    = (const float*)d_in[2];
  const float* b1    = (const float*)d_in[3];
  const float* W2    = (const float*)d_in[4];
  const float* b2    = (const float*)d_in[5];
  const float* Wout  = (const float*)d_in[6];
  const float* bout  = (const float*)d_in[7];
  const float* ke_lw = (const float*)d_in[8];
  const float* ke_iw = (const float*)d_in[9];
  float* out = (float*)d_out;
  u32x4* pack = (u32x4*)d_ws;   // 74*22*64*16 B = 1.63 MB

  k0w_pack<<<74, 64, 0, stream>>>(W1, b1, W2, b2, Wout, pack);
  k0_init<<<29 * 128, 256, 0, stream>>>(comp, ke_lw, ke_iw, out);
  k1_mlp<<<1184, 256, 0, stream>>>(t_p, comp, pack, bout, out);
}

// Round 8
// 112.015 us; speedup vs baseline: 1.4006x; 1.0145x over previous
//
#include <hip/hip_runtime.h>

#define NPTS 32768

typedef _Float16 f16;
typedef _Float16 f16x2 __attribute__((ext_vector_type(2)));
typedef _Float16 f16x8 __attribute__((ext_vector_type(8)));
typedef float f32x2 __attribute__((ext_vector_type(2)));
typedef float f32x4 __attribute__((ext_vector_type(4)));
typedef unsigned int u32x4 __attribute__((ext_vector_type(4)));

union U16 { u32x4 u; f32x4 f; f16x2 h2[4]; f16x8 h8; };

static __device__ __forceinline__ f16x2 pk_fma(f16x2 a, f16x2 b, f16x2 c) {
  return __builtin_elementwise_fma(a, b, c);
}
static __device__ __forceinline__ f16x2 pk_relu(f16x2 a) {
  f16x2 z = {(f16)0.f, (f16)0.f};
  return __builtin_elementwise_max(a, z);
}
static __device__ __forceinline__ f16x2 pk_cvt(float a, float b) {
  return __builtin_bit_cast(f16x2, __builtin_amdgcn_cvt_pkrtz(a, b));
}

// Per used-gas (gi = 0..73) tables (h2o nets 7,8 unused downstream):
__device__ const unsigned char G_T[74] = {
  0,0,0,0,0,0,0, 0,0,0,0,0,0,0,0,0,0,0,0,0,0,0,0,0,0,0,0,
  1,1,1,1,1,1,1,1,1,1,1,1,1,
  2,2,2,2,2,2,2,2,2,
  3,3,3,
  4,4,4,4,4,4,4,4,4,
  5,5,5,5,5,5,5,5,5,5,5,5,5
};
__device__ const unsigned char G_C1[74] = {
  0,1,2,3,4,5,6, 9,10,11,12,13,14,15,16,17,18,19,20,21,22,23,24,25,26,27,28,
  0,1,2,17,18,19,20,21,22,25,26,27,28,
  0,1,2,5,6,9,10,13,14,
  0,1,2,
  0,1,2,3,4,7,8,11,12,
  0,1,2,15,16,17,18,19,20,21,22,27,28
};
__device__ const unsigned char G_C2[74] = {
  255,255,255,7,8,255,255, 255,255,255,255,255,255,255,255,255,255,255,255,
  255,255,255,255,255,255,255,255,
  255,255,255,255,255,255,255,255,255,255,255,255,255,
  255,255,255,255,255,255,255,255,255,
  255,255,255,
  255,255,255,255,255,255,255,255,255,
  255,255,255,255,255,255,255,255,255,255,255,255,255
};

// Packed-weight layout in d_ws: uint4 slots, addr = ((gi*22 + slot)*64 + lane).
#define NSLOT 22

// ---------------------------------------------------------------------------
// k0w: repack weights into fragment-ready lane order. 74 blocks x 64 threads.
// ---------------------------------------------------------------------------
__global__ __launch_bounds__(64) void k0w_pack(
    const float* __restrict__ W1, const float* __restrict__ b1,
    const float* __restrict__ W2, const float* __restrict__ b2,
    const float* __restrict__ Wout, u32x4* __restrict__ pack)
{
  const int gi   = blockIdx.x;
  const int lane = threadIdx.x;
  const int l15  = lane & 15;
  const int quad = lane >> 4;
  const int g    = gi + (gi >= 7 ? 2 : 0);

  const float* W2g = W2 + g * 4096;
  const float* W1g = W1 + g * 128;
  const float* b1g = b1 + g * 64;
  u32x4* dst = pack + gi * NSLOT * 64 + lane;

  #pragma unroll
  for (int mt = 0; mt < 4; ++mt)
    #pragma unroll
    for (int ks = 0; ks < 2; ++ks) {
      U16 u;
      #pragma unroll
      for (int j = 0; j < 4; ++j) {
        const float* s = W2g + (ks * 32 + quad * 8 + 2 * j) * 64 + mt * 16 + l15;
        u.h2[j] = pk_cvt(s[0], s[64]);
      }
      dst[(mt * 2 + ks) * 64] = u.u;
    }
  #pragma unroll
  for (int ks = 0; ks < 2; ++ks) {
    U16 a, b, c;
    #pragma unroll
    for (int j = 0; j < 4; ++j) {
      int h = ks * 32 + quad * 8 + 2 * j;
      a.h2[j] = pk_cvt(W1g[h],      W1g[h + 1]);
      b.h2[j] = pk_cvt(W1g[64 + h], W1g[64 + h + 1]);
      c.h2[j] = pk_cvt(b1g[h],      b1g[h + 1]);
    }
    dst[(8 + ks) * 64]  = a.u;
    dst[(10 + ks) * 64] = b.u;
    dst[(12 + ks) * 64] = c.u;
  }
  #pragma unroll
  for (int mt = 0; mt < 4; ++mt) {
    U16 u, v;
    u.f = *(const f32x4*)(b2   + g * 64 + mt * 16 + quad * 4);
    v.f = *(const f32x4*)(Wout + g * 64 + mt * 16 + quad * 4);
    dst[(14 + mt) * 64] = u.u;
    dst[(18 + mt) * 64] = v.u;
  }
}

// ---------------------------------------------------------------------------
// k0: zero the gases section of out, write tau_lw / tau_iw.
// ---------------------------------------------------------------------------
__global__ __launch_bounds__(256) void k0_init(
    const float* __restrict__ comp, const float* __restrict__ ke_lw,
    const float* __restrict__ ke_iw, float* __restrict__ out)
{
  const int c = blockIdx.x >> 7;
  const int n = ((blockIdx.x & 127) << 8) + threadIdx.x;
  out[c * NPTS + n] = 0.f;
  out[29 * NPTS + c * NPTS + n] = ke_lw[c] * comp[6 * NPTS + n];
  out[58 * NPTS + c * NPTS + n] = ke_iw[c] * comp[7 * NPTS + n];
}

// ---------------------------------------------------------------------------
// k1: per-gas MLP (2->64->64->1) fused with channel scatter.
// Fully-unrolled 8-pass loop with depth-1 input prefetch: pass p+1's t_p/comp
// loads issue before pass p's compute, so memory latency and the shuffle
// tail overlap with VALU/MFMA work (software pipeline).
// NOTE: (256,2) bound — (256,4) capped VGPRs at 64 and spilled to scratch
// (R6: FETCH 90 MB, 85 us). Do not lower the register budget.
// ---------------------------------------------------------------------------
__global__ __launch_bounds__(256, 2) void k1_mlp(
    const float* __restrict__ t_p, const float* __restrict__ comp,
    const u32x4* __restrict__ pack, const float* __restrict__ bout,
    float* __restrict__ out)
{
  const int lane = threadIdx.x & 63;
  const int l15  = lane & 15;
  const int quad = lane >> 4;
  const int w    = blockIdx.x * 4 + (threadIdx.x >> 6);
  const int gi   = w >> 6;                 // 0..73
  const int g    = gi + (gi >= 7 ? 2 : 0);
  const int pb0  = (w & 63) * 512;

  const int t  = G_T[gi];
  const int c1 = G_C1[gi];
  const int c2 = G_C2[gi];   // 255 = none

  const bool qb0 = (quad & 1) != 0;
  const bool qb1 = (quad & 2) != 0;

  // ---- coalesced fragment loads, directly into typed registers
  const u32x4* pksrc = pack + gi * NSLOT * 64 + lane;
  f16x8 afrag[4][2];
  f32x4 b2q[4];
  f32x2 wq2[4][2];
  #pragma unroll
  for (int mt = 0; mt < 4; ++mt) {
    afrag[mt][0] = __builtin_bit_cast(f16x8, pksrc[(mt * 2 + 0) * 64]);
    afrag[mt][1] = __builtin_bit_cast(f16x8, pksrc[(mt * 2 + 1) * 64]);
    b2q[mt] = __builtin_bit_cast(f32x4, pksrc[(14 + mt) * 64]);
    f32x4 wv = __builtin_bit_cast(f32x4, pksrc[(18 + mt) * 64]);
    wq2[mt][0] = f32x2{ wv[0], wv[1] };
    wq2[mt][1] = f32x2{ wv[2], wv[3] };
  }
  U16 w0s[2], w1s[2], b1s[2];
  #pragma unroll
  for (int ks = 0; ks < 2; ++ks) {
    w0s[ks].u = pksrc[(8 + ks) * 64];
    w1s[ks].u = pksrc[(10 + ks) * 64];
    b1s[ks].u = pksrc[(12 + ks) * 64];
  }
  const float bo = bout[g];

  const float2* tp2 = (const float2*)t_p;
  const float* compt = comp + t * NPTS;
  float* out1 = out + c1 * NPTS;
  float* out2 = (c2 == 255) ? nullptr : out + c2 * NPTS;

  // ---- prefetch pass 0 inputs
  float2 xv_n[4];
  float cv_n;
  #pragma unroll
  for (int pt = 0; pt < 4; ++pt)
    xv_n[pt] = tp2[pb0 + pt * 16 + l15];
  cv_n = compt[pb0 + lane];

  #pragma unroll
  for (int pass = 0; pass < 8; ++pass) {
    const int pb = pb0 + pass * 64;

    float2 xv[4];
    #pragma unroll
    for (int pt = 0; pt < 4; ++pt) xv[pt] = xv_n[pt];
    const float cv = cv_n;

    // issue next pass's loads before this pass's compute
    if (pass < 7) {
      const int pbn = pb + 64;
      #pragma unroll
      for (int pt = 0; pt < 4; ++pt)
        xv_n[pt] = tp2[pbn + pt * 16 + l15];
      cv_n = compt[pbn + lane];
    }

    f16x2 x0v[4], x1v[4];
    #pragma unroll
    for (int pt = 0; pt < 4; ++pt) {
      x0v[pt] = pk_cvt(xv[pt].x, xv[pt].x);
      x1v[pt] = pk_cvt(xv[pt].y, xv[pt].y);
    }

    // layer 1 -> B fragments (k = ks*32 + quad*8 + j-pair)
    U16 bfrag[2][4];
    #pragma unroll
    for (int ks = 0; ks < 2; ++ks)
      #pragma unroll
      for (int pt = 0; pt < 4; ++pt)
        #pragma unroll
        for (int i = 0; i < 4; ++i)
          bfrag[ks][pt].h2[i] =
              pk_relu(pk_fma(x0v[pt], w0s[ks].h2[i],
                             pk_fma(x1v[pt], w1s[ks].h2[i], b1s[ks].h2[i])));

    // layer 2 + per-mt layer-3 fold (acc liveness = 16 regs)
    f32x2 p2[4];
    #pragma unroll
    for (int pt = 0; pt < 4; ++pt) p2[pt] = f32x2{ 0.f, 0.f };

    #pragma unroll
    for (int mt = 0; mt < 4; ++mt) {
      f32x4 c[4];
      #pragma unroll
      for (int pt = 0; pt < 4; ++pt)
        c[pt] = __builtin_amdgcn_mfma_f32_16x16x32_f16(
            afrag[mt][0], bfrag[0][pt].h8, b2q[mt], 0, 0, 0);
      #pragma unroll
      for (int pt = 0; pt < 4; ++pt)
        c[pt] = __builtin_amdgcn_mfma_f32_16x16x32_f16(
            afrag[mt][1], bfrag[1][pt].h8, c[pt], 0, 0, 0);
      #pragma unroll
      for (int pt = 0; pt < 4; ++pt) {
        f32x2 z = { 0.f, 0.f };
        f32x2 a0 = { c[pt][0], c[pt][1] };
        f32x2 a1 = { c[pt][2], c[pt][3] };
        a0 = __builtin_elementwise_max(a0, z);
        a1 = __builtin_elementwise_max(a1, z);
        p2[pt] = __builtin_elementwise_fma(a0, wq2[mt][0], p2[pt]);
        p2[pt] = __builtin_elementwise_fma(a1, wq2[mt][1], p2[pt]);
      }
    }

    float p[4];
    #pragma unroll
    for (int pt = 0; pt < 4; ++pt) p[pt] = p2[pt][0] + p2[pt][1];

    // quad transpose-reduce: 3 shuffles, 4 results (one per quad)
    float u  = qb1 ? (qb0 ? p[3] : p[2]) : (qb0 ? p[1] : p[0]);
    float v  = qb1 ? (qb0 ? p[2] : p[3]) : (qb0 ? p[0] : p[1]);
    float w2 = qb1 ? (qb0 ? p[1] : p[0]) : (qb0 ? p[3] : p[2]);
    float x  = qb1 ? (qb0 ? p[0] : p[1]) : (qb0 ? p[2] : p[3]);
    float s  = u + __shfl_xor(v, 16, 64);
    float tt = w2 + __shfl_xor(x, 16, 64);
    float r  = s + __shfl_xor(tt, 32, 64);

    float tau = fmaxf(r + bo, 0.f) * cv;
    atomicAdd(&out1[pb + lane], tau);
    if (out2) atomicAdd(&out2[pb + lane], tau);
  }
}

// ---------------------------------------------------------------------------
extern "C" void kernel_launch(void* const* d_in, const int* in_sizes, int n_in,
                              void* d_out, int out_size, void* d_ws, size_t ws_size,
                              hipStream_t stream)
{
  const float* t_p   = (const float*)d_in[0];
  const float* comp  = (const float*)d_in[1];
  const float* W1    = (const float*)d_in[2];
  const float* b1    = (const float*)d_in[3];
  const float* W2    = (const float*)d_in[4];
  const float* b2    = (const float*)d_in[5];
  const float* Wout  = (const float*)d_in[6];
  const float* bout  = (const float*)d_in[7];
  const float* ke_lw = (const float*)d_in[8];
  const float* ke_iw = (const float*)d_in[9];
  float* out = (float*)d_out;
  u32x4* pack = (u32x4*)d_ws;   // 74*22*64*16 B = 1.63 MB

  k0w_pack<<<74, 64, 0, stream>>>(W1, b1, W2, b2, Wout, pack);
  k0_init<<<29 * 128, 256, 0, stream>>>(comp, ke_lw, ke_iw, out);
  k1_mlp<<<1184, 256, 0, stream>>>(t_p, comp, pack, bout, out);
}